// Round 3
// baseline (291.882 us; speedup 1.0000x reference)
//
#include <hip/hip_runtime.h>
#include <math.h>

// TopK router: logits = x(N,2048) @ W(64,2048)^T, softmax, top-2, renorm.
// Output: [weights 2N floats][indices 2N floats]
//
// Tiling: block = 256 threads, BM = 64 tokens/block -> 256 blocks = 1/CU.
// Thread tile 4 tokens x 4 experts. W k-tile in LDS; x streamed from global
// (float4, lane-broadcast within 16-lane e-groups -> L1/cacheline friendly).

#define TK_D 2048
#define TK_E 64
#define TK_BM 64
#define TK_BK 128
#define TK_MI 4
#define TK_EI 4

__global__ __launch_bounds__(256, 1)
void topk_router_kernel(const float* __restrict__ x,
                        const float* __restrict__ W,
                        float* __restrict__ out, int N) {
    // +4 float pad: row stride 132 -> 4-bank rotation per row, 2-way (free) on reads
    __shared__ float wlds[TK_E][TK_BK + 4];

    const int tid = threadIdx.x;
    const int eg  = tid & 15;   // expert group (lane bits 0..3)
    const int mg  = tid >> 4;   // token group 0..15 (spans waves)
    const int base = blockIdx.x * TK_BM;

    const float* xr[TK_MI];
#pragma unroll
    for (int mi = 0; mi < TK_MI; ++mi)
        xr[mi] = x + (size_t)(base + mg + 16 * mi) * TK_D;

    float acc[TK_MI][TK_EI];
#pragma unroll
    for (int mi = 0; mi < TK_MI; ++mi)
#pragma unroll
        for (int ei = 0; ei < TK_EI; ++ei) acc[mi][ei] = 0.f;

    for (int kt = 0; kt < TK_D / TK_BK; ++kt) {
        __syncthreads();
        // stage W[0..63][kt*BK .. +BK): 2048 float4, 8 per thread
#pragma unroll
        for (int j = 0; j < (TK_E * TK_BK / 4) / 256; ++j) {
            int s   = tid + 256 * j;
            int row = s >> 5;        // BK/4 = 32 float4 per row
            int c4  = s & 31;
            float4 v = *(const float4*)(W + (size_t)row * TK_D + kt * TK_BK + c4 * 4);
            *(float4*)&wlds[row][c4 * 4] = v;
        }
        __syncthreads();

#pragma unroll 8
        for (int kk = 0; kk < TK_BK / 4; ++kk) {
            float4 xv[TK_MI], wv[TK_EI];
#pragma unroll
            for (int mi = 0; mi < TK_MI; ++mi)
                xv[mi] = *(const float4*)(xr[mi] + kt * TK_BK + kk * 4);
#pragma unroll
            for (int ei = 0; ei < TK_EI; ++ei)
                wv[ei] = *(const float4*)&wlds[eg + 16 * ei][kk * 4];
#pragma unroll
            for (int mi = 0; mi < TK_MI; ++mi)
#pragma unroll
                for (int ei = 0; ei < TK_EI; ++ei) {
                    acc[mi][ei] = fmaf(xv[mi].x, wv[ei].x, acc[mi][ei]);
                    acc[mi][ei] = fmaf(xv[mi].y, wv[ei].y, acc[mi][ei]);
                    acc[mi][ei] = fmaf(xv[mi].z, wv[ei].z, acc[mi][ei]);
                    acc[mi][ei] = fmaf(xv[mi].w, wv[ei].w, acc[mi][ei]);
                }
        }
    }

    float* outw = out;
    float* outi = out + 2 * (size_t)N;

    // Epilogue: per token (64 logits spread over 16 lanes x 4 regs),
    // top-2 with jax.lax.top_k tie semantics (lower index first), softmax sum.
#pragma unroll
    for (int mi = 0; mi < TK_MI; ++mi) {
        float v1 = -3.0e38f, v2 = -3.0e38f;
        int   i1 = 0, i2 = 0;
#pragma unroll
        for (int ei = 0; ei < TK_EI; ++ei) {
            float v  = acc[mi][ei];
            int  idx = eg + 16 * ei;
            if (v > v1)      { v2 = v1; i2 = i1; v1 = v; i1 = idx; }
            else if (v > v2) { v2 = v;  i2 = idx; }
        }
#pragma unroll
        for (int xm = 1; xm <= 8; xm <<= 1) {
            float ov1 = __shfl_xor(v1, xm);
            int   oi1 = __shfl_xor(i1, xm);
            float ov2 = __shfl_xor(v2, xm);
            int   oi2 = __shfl_xor(i2, xm);
            bool owin = (ov1 > v1) || (ov1 == v1 && oi1 < i1);
            if (owin) {
                bool sw = (v1 > ov2) || (v1 == ov2 && i1 < oi2);
                v2 = sw ? v1 : ov2; i2 = sw ? i1 : oi2;
                v1 = ov1; i1 = oi1;
            } else {
                bool sw = (ov1 > v2) || (ov1 == v2 && oi1 < i2);
                v2 = sw ? ov1 : v2; i2 = sw ? oi1 : i2;
            }
        }
        float s = 0.f;
#pragma unroll
        for (int ei = 0; ei < TK_EI; ++ei)
            s += expf(acc[mi][ei] - v1);
#pragma unroll
        for (int xm = 1; xm <= 8; xm <<= 1)
            s += __shfl_xor(s, xm);

        if (eg == 0) {
            int token = base + mg + 16 * mi;
            float p1 = 1.0f / s;             // exp(v1 - v1) / s
            float p2 = expf(v2 - v1) / s;
            float dn = p1 + p2 + 1e-9f;
            outw[2 * (size_t)token]     = p1 / dn;
            outw[2 * (size_t)token + 1] = p2 / dn;
            outi[2 * (size_t)token]     = (float)i1;
            outi[2 * (size_t)token + 1] = (float)i2;
        }
    }
}

extern "C" void kernel_launch(void* const* d_in, const int* in_sizes, int n_in,
                              void* d_out, int out_size, void* d_ws, size_t ws_size,
                              hipStream_t stream) {
    const float* x = (const float*)d_in[0];
    const float* W = (const float*)d_in[1];
    float* out = (float*)d_out;
    int N = in_sizes[0] / TK_D;     // 16384
    int grid = N / TK_BM;           // 256 blocks, 1 per CU
    topk_router_kernel<<<grid, 256, 0, stream>>>(x, W, out, N);
}